// Round 9
// baseline (188.439 us; speedup 1.0000x reference)
//
#include <hip/hip_runtime.h>
#include <hip/hip_bf16.h>

#define B_N 32
#define C_K 512
#define T_N 1024
#define D_M 512

constexpr int BM = 128, BN = 128, BK = 32;
constexpr int SA = 32;            // shorts per LDS row (64B): best geometry (r6)
constexpr int KSTEPS = C_K / BK;  // 16

typedef __attribute__((ext_vector_type(4))) float  floatx4;
typedef __attribute__((ext_vector_type(8))) short  shortx8;
typedef __attribute__((ext_vector_type(4))) unsigned int uintx4;

__device__ __forceinline__ unsigned pk2(float a, float b) {
  __hip_bfloat162 h = __float22bfloat162_rn(make_float2(a, b));
  union { __hip_bfloat162 v; unsigned u; } c; c.v = h; return c.u;
}

// Raw workgroup barrier: LDS ops drained (lgkmcnt 0) but global
// loads-to-register stay IN FLIGHT across it. __syncthreads drains vmcnt(0),
// which would cut each tile's load flight back to frags+MFMA (~250cy).
__device__ __forceinline__ void wg_barrier() {
  asm volatile("s_waitcnt lgkmcnt(0)" ::: "memory");
  __builtin_amdgcn_s_barrier();
  __builtin_amdgcn_sched_barrier(0);
}

// out[b,d,t] = sum_c x[b,c,t] * W[sub[b],c,d] + bias[sub[b],d]
// Per-b GEMM: A = W[nb] (K x M, m-contig), B = X[b] (K x N, n-contig)
//
// LDS (round 6 geometry, best): [row][k] bf16, SA=32 (64B rows), 32,768B/block.
// Swizzle on 16B k-chunks: phys_q = q ^ ((row>>4)&3).
//   Reads: ONE ds_read_b128 per fragment, 8 lanes/16B-slot = floor (critical path).
//   Writes: 16 lanes/slot = 2x floor (8.39M cy) — PROVEN benign by two A/Bs:
//     r0->r3 (-4.19M cy: dur +-0) and r6->r7 (-4.2M cy via SA=40: dur REGRESSED).
//
// Pipeline (round 8/9): depth-1 registers, depth-2 TIMING. The staging regs v[]
// die at cvt, so the next tile's loads issue at the TAIL of the previous step:
//   flight = cvt tail + barrier + frag reads + MFMA  (~1 full kstep, ~600cy)
// vs round 6's post-barrier issue (~250cy flight). Requires wg_barrier (raw
// s_barrier, no vmcnt drain). Zero extra registers — depth-2 register prefetch
// is dead (r5: spill, WRITE 65->294MB); occupancy levers dead (r4/r6: LDS pool
// caps at 3 blocks/CU regardless).
// (Round 8 bench aborted on container infra failure; round 9 = clean resubmit.)
__global__ __launch_bounds__(256, 3)
void subject_gemm(const float* __restrict__ x, const int* __restrict__ subjects,
                  const float* __restrict__ weights, const float* __restrict__ bias,
                  float* __restrict__ out)
{
  __shared__ __align__(16) short lds_a[2][BM * SA]; // [m][k] bf16 (chunk16-swizzled)
  __shared__ __align__(16) short lds_b[2][BN * SA]; // [n][k]

  // XCD-aware swizzle: all 32 tiles of a batch land on one XCD.
  const int bid  = blockIdx.x;
  const int xcd  = bid & 7;
  const int s    = bid >> 3;           // 0..127
  const int b    = xcd * 4 + (s & 3);  // 4 batches per XCD
  const int tile = s >> 2;             // 0..31
  const int tm = tile >> 3, tn = tile & 7;
  const int m0 = tm * BM, n0 = tn * BN;
  const int nb = subjects[b];

  const float* __restrict__ Wp = weights + (size_t)nb * C_K * D_M; // [k][m]
  const float* __restrict__ Xp = x + (size_t)b * C_K * T_N;        // [k][n]

  const int tid  = threadIdx.x;
  const int lane = tid & 63;
  const int wave = tid >> 6;

  // ---- staging role: waves 0-1 stage A, waves 2-3 stage B ----
  const bool isA = (wave < 2);
  const int  mg  = (wave & 1) * 16 + (lane & 15); // rows 4*mg..4*mg+3
  const int  oct = lane >> 4;                     // k-chunk16; k = 8*oct + jj
  const float* gsrc = isA ? (Wp + (size_t)(8 * oct) * D_M + (m0 + 4 * mg))
                          : (Xp + (size_t)(8 * oct) * T_N + (n0 + 4 * mg));
  const int gs = isA ? D_M : T_N;
  const int sw   = (mg >> 2) & 3;                 // s(row)=(row>>4)&3
  const int cOff = 8 * (oct ^ sw);                // short offset of phys chunk16
  short* const wbase = (isA ? &lds_a[0][0] : &lds_b[0][0]) + (4 * mg) * SA + cOff;
  constexpr int BUFO = BM * SA;

  // ---- compute role: 4 waves, 64x64 tiles ----
  const int wm = (wave & 1) * 64, wn = (wave >> 1) * 64;
  const int l15 = lane & 15, q = lane >> 4;

  floatx4 acc[4][4] = {};
  floatx4 v[8];

  auto loads = [&]() {
    #pragma unroll
    for (int jj = 0; jj < 8; ++jj)
      v[jj] = *(const floatx4*)(gsrc + (size_t)jj * gs);
    gsrc += (size_t)BK * gs;
  };
  auto cvt_store = [&](int p) {   // vmcnt wait for v[] lands at first pk2 here
    short* wdst = wbase + p * BUFO;
    #pragma unroll
    for (int r = 0; r < 4; ++r) {
      uintx4 pk = { pk2(v[0][r], v[1][r]), pk2(v[2][r], v[3][r]),
                    pk2(v[4][r], v[5][r]), pk2(v[6][r], v[7][r]) };
      *(uintx4*)(wdst + r * SA) = pk;
    }
  };

  // ---- prologue ----
  loads();            // tile 0
  cvt_store(0);       // one-time vmcnt(0)
  loads();            // tile 1 — in flight across barrier + step-0 frags + MFMA

  for (int ks = 0; ks < KSTEPS; ++ks) {
    const int p = ks & 1;
    wg_barrier();     // buf p ready; in-flight loads survive the barrier

    // fragments from buf p: single b128 each, phys chunk = q ^ i (wave-uniform)
    const short* pa = &lds_a[p][0] + (wm + l15) * SA;
    const short* pb = &lds_b[p][0] + (wn + l15) * SA;
    shortx8 af[4], bg[4];
    #pragma unroll
    for (int i = 0; i < 4; ++i) {
      af[i] = *(const shortx8*)(pa + 16 * i * SA + 8 * (q ^ i));
      bg[i] = *(const shortx8*)(pb + 16 * i * SA + 8 * (q ^ i));
    }
    #pragma unroll
    for (int i = 0; i < 4; ++i)
      #pragma unroll
      for (int j = 0; j < 4; ++j)
        acc[i][j] = __builtin_amdgcn_mfma_f32_16x16x32_bf16(af[i], bg[j], acc[i][j], 0, 0, 0);

    // tail: consume v (tile ks+1) into buf p^1, then immediately re-issue
    // loads for tile ks+2 — they fly through the next barrier + compute.
    if (ks + 1 < KSTEPS) cvt_store(p ^ 1);
    if (ks + 2 < KSTEPS) loads();
  }

  // ---- epilogue: col = lane&15 (t), row = 4q + r (d) ----
  float* __restrict__ O = out + (size_t)b * D_M * T_N;
  const float* __restrict__ bb = bias + (size_t)nb * D_M;
  #pragma unroll
  for (int i = 0; i < 4; ++i) {
    #pragma unroll
    for (int r = 0; r < 4; ++r) {
      const int d = m0 + wm + 16 * i + 4 * q + r;
      const float bv = bb[d];
      #pragma unroll
      for (int j = 0; j < 4; ++j) {
        const int t = n0 + wn + 16 * j + l15;
        O[(size_t)d * T_N + t] = acc[i][j][r] + bv;
      }
    }
  }
}

extern "C" void kernel_launch(void* const* d_in, const int* in_sizes, int n_in,
                              void* d_out, int out_size, void* d_ws, size_t ws_size,
                              hipStream_t stream) {
  const float* x        = (const float*)d_in[0];
  const int*   subjects = (const int*)d_in[1];
  const float* weights  = (const float*)d_in[2];
  const float* bias     = (const float*)d_in[3];
  float* out = (float*)d_out;
  (void)in_sizes; (void)n_in; (void)out_size; (void)d_ws; (void)ws_size;

  dim3 grid(B_N * 4 * 8); // 1024 blocks: 32 b x 4 tm x 8 tn
  dim3 block(256);
  hipLaunchKernelGGL(subject_gemm, grid, block, 0, stream, x, subjects, weights, bias, out);
}